// Round 1
// baseline (1482.977 us; speedup 1.0000x reference)
//
#include <hip/hip_runtime.h>

typedef _Float16 half_t;
typedef _Float16 halfv8 __attribute__((ext_vector_type(8)));
typedef _Float16 halfv4 __attribute__((ext_vector_type(4)));
typedef float    floatv4 __attribute__((ext_vector_type(4)));

#define NODES 32
#define FIN   128
#define EPG   512
#define NBS   4096
#define ETOT  (NBS*EPG)
#define HID   1024
#define KDIM  4096   // FIN*NODES
#define NCLS  10

// async global->LDS, 16B per lane (dest = wave-uniform base + lane*16)
#define GLDS16(g, l)                                                        \
  __builtin_amdgcn_global_load_lds(                                         \
      (const __attribute__((address_space(1))) unsigned int*)(g),           \
      (__attribute__((address_space(3))) unsigned int*)(l), 16, 0, 0)

// ---------------------------------------------------------------------------
// prep: gconv_w fp32 -> fp16 (same [o][k] layout)
__global__ __launch_bounds__(256) void prep_gw(const float* __restrict__ gw,
                                               half_t* __restrict__ gw16) {
  int i = blockIdx.x * 256 + threadIdx.x;   // grid 64 -> 16384
  gw16[i] = (half_t)gw[i];
}

// prep: lin1_w fp32 [o][f*32+n] -> fp16 permuted [o][n*128+f]
__global__ __launch_bounds__(256) void prep_w1(const float* __restrict__ w1,
                                               half_t* __restrict__ w1p) {
  __shared__ float tmp[FIN * 33];           // [f][n] padded (+1) for bank spread
  const int o = blockIdx.x, t = threadIdx.x;
  const floatv4* src = (const floatv4*)(w1 + (size_t)o * KDIM);
  for (int i = t; i < KDIM / 4; i += 256) {
    floatv4 v = src[i];
    const int f = i >> 3;
    const int n = (i & 7) * 4;
#pragma unroll
    for (int q = 0; q < 4; ++q) tmp[f * 33 + n + q] = v[q];
  }
  __syncthreads();
  half_t* dst = w1p + (size_t)o * KDIM;
  for (int i = t; i < KDIM; i += 256) {
    const int n = i >> 7, f = i & 127;
    dst[i] = (half_t)tmp[f * 33 + n];
  }
}

// ---------------------------------------------------------------------------
// Fused GIN conv: one block per graph.
// agg(=x + scatter-add) in LDS -> fp16 -> MFMA with gconv_w -> relu ->
// H[g][node*128 + feat]  (fp16)
__global__ __launch_bounds__(256) void gin_conv(
    const float* __restrict__ x, const int* __restrict__ ei,
    const half_t* __restrict__ gw16, const float* __restrict__ gb,
    half_t* __restrict__ H) {
  __shared__ __attribute__((aligned(16))) float xs[NODES * FIN];    // 16 KB
  __shared__ __attribute__((aligned(16))) float agg[NODES * FIN];   // 16 KB
  __shared__ int esrc[EPG];                                         // 2 KB
  __shared__ int edst[EPG];                                         // 2 KB
  __shared__ __attribute__((aligned(16))) half_t a16[NODES * 136];  // 8.5 KB
  __shared__ __attribute__((aligned(16))) half_t b16[FIN * 136];    // 34 KB

  const int g = blockIdx.x;
  const int t = threadIdx.x;

  // stage x; init agg = x (GIN eps=0: h = x_i + sum_j x_j)
  const floatv4* xg = (const floatv4*)(x + (size_t)g * (NODES * FIN));
  floatv4* xs4 = (floatv4*)xs;
  floatv4* ag4 = (floatv4*)agg;
#pragma unroll
  for (int i = 0; i < 4; ++i) {
    floatv4 v = xg[t + i * 256];
    xs4[t + i * 256] = v;
    ag4[t + i * 256] = v;
  }
  // edges of this graph are contiguous; local id = idx & 31
  const int* sp = ei + (size_t)g * EPG;
  const int* dp = ei + (size_t)ETOT + (size_t)g * EPG;
  for (int i = t; i < EPG; i += 256) {
    esrc[i] = sp[i] & (NODES - 1);
    edst[i] = dp[i] & (NODES - 1);
  }
  // stage gconv_w fp16 into LDS, row-padded to 136 halfs (16B-aligned rows)
  {
    const halfv8* gsrc = (const halfv8*)gw16;
    for (int i = t; i < (FIN * FIN) / 8; i += 256) {
      const int row = i >> 4, c8 = i & 15;
      *(halfv8*)&b16[row * 136 + c8 * 8] = gsrc[i];
    }
  }
  __syncthreads();
  // scatter-add: thread = (feature f, edge-half eh); 256 edges each
  {
    const int f = t & 127, eh = t >> 7;
    for (int c = 0; c < EPG / 2; ++c) {
      const int e = 2 * c + eh;
      atomicAdd(&agg[edst[e] * FIN + f], xs[esrc[e] * FIN + f]);
    }
  }
  __syncthreads();
  // fp32 -> fp16 fragment tile
  for (int i = t; i < NODES * FIN; i += 256)
    a16[(i >> 7) * 136 + (i & 127)] = (half_t)agg[i];
  __syncthreads();

  // MFMA: per wave 16 nodes x 64 out-feats; K=128 in 4 steps of 32
  const int w = t >> 6, l = t & 63;
  const int lr = l & 15, lk = l >> 4;
  const int m0 = (w & 1) * 16, o0 = (w >> 1) * 64;
  floatv4 acc[4] = {{0,0,0,0},{0,0,0,0},{0,0,0,0},{0,0,0,0}};
#pragma unroll
  for (int kk = 0; kk < 4; ++kk) {
    halfv8 af = *(const halfv8*)&a16[(m0 + lr) * 136 + kk * 32 + lk * 8];
#pragma unroll
    for (int nf = 0; nf < 4; ++nf) {
      halfv8 bf = *(const halfv8*)&b16[(o0 + nf * 16 + lr) * 136 + kk * 32 + lk * 8];
      acc[nf] = __builtin_amdgcn_mfma_f32_16x16x32_f16(af, bf, acc[nf], 0, 0, 0);
    }
  }
  // bias + relu + store (node-major: H[g][m*128 + o])
  half_t* Hg = H + (size_t)g * KDIM;
#pragma unroll
  for (int nf = 0; nf < 4; ++nf) {
    const int o = o0 + nf * 16 + lr;
    const float bias = gb[o];
#pragma unroll
    for (int j = 0; j < 4; ++j) {
      const int m = m0 + lk * 4 + j;
      const float v = acc[nf][j] + bias;
      Hg[m * FIN + o] = (half_t)(v > 0.f ? v : 0.f);
    }
  }
}

// ---------------------------------------------------------------------------
// lin1 GEMM: C[m][n] = sum_k H[m][k] * w1p[n][k]; split-K=2 -> two fp16
// partial buffers. m97 structure: 128x128 tile, BK=32, 4 waves, gload_lds.
__global__ __launch_bounds__(256) void lin1_gemm(
    const half_t* __restrict__ A, const half_t* __restrict__ B,
    half_t* __restrict__ Cbase) {
  __shared__ __attribute__((aligned(16))) half_t As[128 * 32];  // 8 KB
  __shared__ __attribute__((aligned(16))) half_t Bs[128 * 32];  // 8 KB
  const int t = threadIdx.x;
  const int m0 = blockIdx.x * 128;
  const int n0 = blockIdx.y * 128;
  const int kz = blockIdx.z;
  const int k0 = kz * (KDIM / 2);
  half_t* C = Cbase + (size_t)kz * ((size_t)NBS * HID);

  const int w = t >> 6, l = t & 63;
  const int lr = l & 15, lk = l >> 4;
  const int wm = (w & 1) * 64, wn = (w >> 1) * 64;

  const int ch0 = t, ch1 = t + 256;           // 16B chunks of the 8KB tile
  const int r0 = ch0 >> 2, c0_ = (ch0 & 3) * 8;
  const int r1 = ch1 >> 2, c1_ = (ch1 & 3) * 8;
  const half_t* gA0 = A + (size_t)(m0 + r0) * KDIM + k0 + c0_;
  const half_t* gA1 = A + (size_t)(m0 + r1) * KDIM + k0 + c1_;
  const half_t* gB0 = B + (size_t)(n0 + r0) * KDIM + k0 + c0_;
  const half_t* gB1 = B + (size_t)(n0 + r1) * KDIM + k0 + c1_;

  floatv4 acc[4][4] = {};

  for (int kt = 0; kt < 64; ++kt) {
    GLDS16(gA0, &As[ch0 * 8]);
    GLDS16(gA1, &As[ch1 * 8]);
    GLDS16(gB0, &Bs[ch0 * 8]);
    GLDS16(gB1, &Bs[ch1 * 8]);
    gA0 += 32; gA1 += 32; gB0 += 32; gB1 += 32;
    __syncthreads();   // drains vmcnt before barrier (compiler-inserted)

    halfv8 af[4], bf[4];
#pragma unroll
    for (int mf = 0; mf < 4; ++mf)
      af[mf] = *(const halfv8*)&As[(wm + mf * 16 + lr) * 32 + lk * 8];
#pragma unroll
    for (int nf = 0; nf < 4; ++nf)
      bf[nf] = *(const halfv8*)&Bs[(wn + nf * 16 + lr) * 32 + lk * 8];
#pragma unroll
    for (int mf = 0; mf < 4; ++mf)
#pragma unroll
      for (int nf = 0; nf < 4; ++nf)
        acc[mf][nf] = __builtin_amdgcn_mfma_f32_16x16x32_f16(af[mf], bf[nf],
                                                             acc[mf][nf], 0, 0, 0);
    __syncthreads();
  }
  // store fp16 partials
#pragma unroll
  for (int mf = 0; mf < 4; ++mf)
#pragma unroll
    for (int nf = 0; nf < 4; ++nf) {
      const int n = n0 + wn + nf * 16 + lr;
#pragma unroll
      for (int j = 0; j < 4; ++j) {
        const int m = m0 + wm + mf * 16 + lk * 4 + j;
        C[(size_t)m * HID + n] = (half_t)acc[mf][nf][j];
      }
    }
}

// ---------------------------------------------------------------------------
// head: hidden = relu(C0+C1+b1); logits = hidden @ w2^T + b2; softmax -> out
// one wave per graph row; lane owns 16 hidden cols as 4 chunks of 4.
__global__ __launch_bounds__(256) void head(
    const half_t* __restrict__ C0, const half_t* __restrict__ C1,
    const float* __restrict__ b1, const float* __restrict__ w2,
    const float* __restrict__ b2, float* __restrict__ out) {
  __shared__ __attribute__((aligned(16))) float w2s[NCLS * HID];  // 40 KB
  const int t = threadIdx.x;
  {
    const floatv4* s4 = (const floatv4*)w2;
    floatv4* d4 = (floatv4*)w2s;
    for (int i = t; i < (NCLS * HID) / 4; i += 256) d4[i] = s4[i];
  }
  __syncthreads();
  const int w = t >> 6, l = t & 63;
  const int row = blockIdx.x * 4 + w;
  const half_t* c0 = C0 + (size_t)row * HID;
  const half_t* c1 = C1 + (size_t)row * HID;

  float r[16];
#pragma unroll
  for (int jj = 0; jj < 4; ++jj) {
    halfv4 u = *(const halfv4*)&c0[jj * 256 + l * 4];
    halfv4 v = *(const halfv4*)&c1[jj * 256 + l * 4];
    floatv4 bb = *(const floatv4*)&b1[jj * 256 + l * 4];
#pragma unroll
    for (int q = 0; q < 4; ++q) {
      const float s = (float)u[q] + (float)v[q] + bb[q];
      r[jj * 4 + q] = s > 0.f ? s : 0.f;
    }
  }
  float lg[10];
#pragma unroll
  for (int c = 0; c < NCLS; ++c) {
    float p = 0.f;
#pragma unroll
    for (int jj = 0; jj < 4; ++jj) {
      floatv4 wv = *(const floatv4*)&w2s[c * HID + jj * 256 + l * 4];
      p += r[jj * 4 + 0] * wv[0] + r[jj * 4 + 1] * wv[1] +
           r[jj * 4 + 2] * wv[2] + r[jj * 4 + 3] * wv[3];
    }
#pragma unroll
    for (int off = 32; off >= 1; off >>= 1) p += __shfl_xor(p, off);
    lg[c] = p + b2[c];
  }
  float mx = lg[0];
#pragma unroll
  for (int c = 1; c < NCLS; ++c) mx = fmaxf(mx, lg[c]);
  float sum = 0.f;
#pragma unroll
  for (int c = 0; c < NCLS; ++c) { lg[c] = __expf(lg[c] - mx); sum += lg[c]; }
  const float inv = 1.f / sum;
  float myv = 0.f;
#pragma unroll
  for (int c = 0; c < NCLS; ++c) myv = (l == c) ? lg[c] * inv : myv;
  if (l < NCLS) out[(size_t)row * NCLS + l] = myv;
}

// ---------------------------------------------------------------------------
extern "C" void kernel_launch(void* const* d_in, const int* in_sizes, int n_in,
                              void* d_out, int out_size, void* d_ws, size_t ws_size,
                              hipStream_t stream) {
  (void)in_sizes; (void)n_in; (void)out_size; (void)ws_size;
  const float* x  = (const float*)d_in[0];
  const int*   ei = (const int*)d_in[1];
  const float* gw = (const float*)d_in[2];
  const float* gb = (const float*)d_in[3];
  const float* w1 = (const float*)d_in[4];
  const float* b1 = (const float*)d_in[5];
  const float* w2 = (const float*)d_in[6];
  const float* b2 = (const float*)d_in[7];
  float* out = (float*)d_out;

  char* ws = (char*)d_ws;
  half_t* H    = (half_t*)(ws);                                  // 33,554,432 B
  half_t* w1p  = (half_t*)(ws + 33554432);                       //  8,388,608 B
  half_t* gw16 = (half_t*)(ws + 33554432 + 8388608);             //     32,768 B
  half_t* C01  = (half_t*)(ws + 33554432 + 8388608 + 32768);     // 2x 8,388,608 B

  prep_gw <<<dim3(64),        dim3(256), 0, stream>>>(gw, gw16);
  prep_w1 <<<dim3(HID),       dim3(256), 0, stream>>>(w1, w1p);
  gin_conv<<<dim3(NBS),       dim3(256), 0, stream>>>(x, ei, gw16, gb, H);
  lin1_gemm<<<dim3(32, 8, 2), dim3(256), 0, stream>>>(H, w1p, C01);
  head    <<<dim3(NBS / 4),   dim3(256), 0, stream>>>(C01, C01 + (size_t)NBS * HID,
                                                      b1, w2, b2, out);
}

// Round 2
// 100.343 us; speedup vs baseline: 14.7791x; 14.7791x over previous
//
#include <hip/hip_runtime.h>

typedef _Float16 half_t;
typedef _Float16 halfv8 __attribute__((ext_vector_type(8)));
typedef _Float16 halfv4 __attribute__((ext_vector_type(4)));
typedef float    floatv4 __attribute__((ext_vector_type(4)));
typedef unsigned int uint;
typedef uint uintv4 __attribute__((ext_vector_type(4)));

#define NODES 32
#define FIN   128
#define EPG   512
#define NBS   4096
#define ETOT  (NBS*EPG)
#define HID   1024
#define KDIM  4096   // FIN*NODES
#define NCLS  10
#define WPITCH 136   // halves; row stride 272B for W in LDS
#define YPITCH 36    // halves; row stride 72B (8B-aligned, bank step 18)

// async global->LDS, 16B per lane (dest = wave-uniform base + lane*16)
#define GLDS16(g, l)                                                        \
  __builtin_amdgcn_global_load_lds(                                         \
      (const __attribute__((address_space(1))) unsigned int*)(g),           \
      (__attribute__((address_space(3))) unsigned int*)(l), 16, 0, 0)

// ---------------------------------------------------------------------------
// prep: lin1_w fp32 [o][f*32+n] -> fp16 permuted [o][n*128+f]
__global__ __launch_bounds__(256) void prep_w1(const float* __restrict__ w1,
                                               half_t* __restrict__ w1p) {
  __shared__ float tmp[FIN * 33];           // [f][n] padded (+1)
  const int o = blockIdx.x, t = threadIdx.x;
  const floatv4* src = (const floatv4*)(w1 + (size_t)o * KDIM);
  for (int i = t; i < KDIM / 4; i += 256) {
    floatv4 v = src[i];
    const int f = i >> 3;
    const int n = (i & 7) * 4;
#pragma unroll
    for (int q = 0; q < 4; ++q) tmp[f * 33 + n + q] = v[q];
  }
  __syncthreads();
  half_t* dst = w1p + (size_t)o * KDIM;
  for (int i = t; i < KDIM; i += 256) {
    const int n = i >> 7, f = i & 127;
    dst[i] = (half_t)tmp[f * 33 + n];
  }
}

// ---------------------------------------------------------------------------
// Fused GIN conv via linearity: H_g = relu( (I + C_g) @ (x_g @ W^T) + b )
// One wave per graph (4 graphs/block). C_g built as a 32x32 u16 histogram
// (packed-u32 LDS int atomics). Both matmuls are fp16 MFMA, fp32 accum.
__global__ __launch_bounds__(256, 2) void gin_fused(
    const float* __restrict__ x, const int* __restrict__ ei,
    const float* __restrict__ gw, const float* __restrict__ gb,
    half_t* __restrict__ H) {
  __shared__ __attribute__((aligned(16))) half_t Ws[FIN * WPITCH];     // 34816 B
  __shared__ __attribute__((aligned(16))) half_t Yt[4][FIN * YPITCH];  // 36864 B
  __shared__ __attribute__((aligned(16))) uint  cnt[4][512];           //  8192 B
  // total 79,872 B -> 2 blocks/CU

  const int t = threadIdx.x, w = t >> 6, l = t & 63;
  const int lr = l & 15, lk = l >> 4;
  const int g = blockIdx.x * 4 + w;

  // (a) issue this wave's x loads (fp32, 32x128) straight into registers
  const float* xg = x + (size_t)g * (NODES * FIN);
  floatv4 xr[2][4][2];
#pragma unroll
  for (int mt = 0; mt < 2; ++mt)
#pragma unroll
    for (int kk = 0; kk < 4; ++kk) {
      const float* p = xg + (mt * 16 + lr) * FIN + kk * 32 + lk * 8;
      xr[mt][kk][0] = *(const floatv4*)p;
      xr[mt][kk][1] = *(const floatv4*)(p + 4);
    }
  // (b) this wave's edges (contiguous per graph; local id = idx & 31)
  const int* sp = ei + (size_t)g * EPG;
  const int* dp = ei + (size_t)ETOT + (size_t)g * EPG;
  uintv4 s0 = *(const uintv4*)(sp + l * 8);
  uintv4 s1 = *(const uintv4*)(sp + l * 8 + 4);
  uintv4 d0 = *(const uintv4*)(dp + l * 8);
  uintv4 d1 = *(const uintv4*)(dp + l * 8 + 4);

  // (c) zero this wave's histogram
  {
    uintv4* c4 = (uintv4*)cnt[w];
    uintv4 z = {0, 0, 0, 0};
    c4[l] = z;
    c4[l + 64] = z;
  }
  // (d) cooperatively stage W (fp32 -> fp16) into LDS, padded rows
  for (int i = t; i < (FIN * FIN) / 4; i += 256) {
    const int o = i >> 5, kc = (i & 31) * 4;
    floatv4 v = *(const floatv4*)(gw + o * FIN + kc);
    halfv4 h = {(half_t)v[0], (half_t)v[1], (half_t)v[2], (half_t)v[3]};
    *(halfv4*)&Ws[o * WPITCH + kc] = h;
  }
  __syncthreads();

  // (e) histogram: cnt16[dst*32+src] += 1 (packed two u16 per u32)
#pragma unroll
  for (int q = 0; q < 4; ++q) {
    uint p0 = (d0[q] & 31) * 32 + (s0[q] & 31);
    atomicAdd(&cnt[w][p0 >> 1], 1u << ((p0 & 1) * 16));
    uint p1 = (d1[q] & 31) * 32 + (s1[q] & 31);
    atomicAdd(&cnt[w][p1 >> 1], 1u << ((p1 & 1) * 16));
  }

  // (f) convert x to fp16 A-fragments
  halfv8 af[2][4];
#pragma unroll
  for (int mt = 0; mt < 2; ++mt)
#pragma unroll
    for (int kk = 0; kk < 4; ++kk) {
      halfv8 h;
#pragma unroll
      for (int q = 0; q < 4; ++q) {
        h[q]     = (half_t)xr[mt][kk][0][q];
        h[q + 4] = (half_t)xr[mt][kk][1][q];
      }
      af[mt][kk] = h;
    }

  // (g) MFMA1: Z[j][o] = sum_f x[j][f] W[o][f]   (2x8 tiles x 4 K-steps)
  floatv4 acc[2][8] = {};
#pragma unroll
  for (int kk = 0; kk < 4; ++kk)
#pragma unroll
    for (int nt = 0; nt < 8; ++nt) {
      halfv8 bf = *(const halfv8*)&Ws[(nt * 16 + lr) * WPITCH + kk * 32 + lk * 8];
#pragma unroll
      for (int mt = 0; mt < 2; ++mt)
        acc[mt][nt] = __builtin_amdgcn_mfma_f32_16x16x32_f16(af[mt][kk], bf,
                                                             acc[mt][nt], 0, 0, 0);
    }

  // (h) bounce Z transposed into this wave's LDS: Yt[o][j]
  half_t* yw = Yt[w];
#pragma unroll
  for (int mt = 0; mt < 2; ++mt)
#pragma unroll
    for (int nt = 0; nt < 8; ++nt) {
      halfv4 h = {(half_t)acc[mt][nt][0], (half_t)acc[mt][nt][1],
                  (half_t)acc[mt][nt][2], (half_t)acc[mt][nt][3]};
      *(halfv4*)&yw[(nt * 16 + lr) * YPITCH + mt * 16 + lk * 4] = h;
    }

  // (i) build M' = I + C fragments from the histogram (u16 reads)
  const unsigned short* c16 = (const unsigned short*)cnt[w];
  halfv8 am[2];
#pragma unroll
  for (int mt = 0; mt < 2; ++mt) {
    const int i = mt * 16 + lr;
#pragma unroll
    for (int q = 0; q < 8; ++q) {
      const int j = lk * 8 + q;
      float c = (float)c16[i * 32 + j] + ((j == i) ? 1.f : 0.f);
      am[mt][q] = (half_t)c;
    }
  }

  // (j) MFMA2: H[i][o] = sum_j M'[i][j] Z[j][o]   (K=32, single step)
  floatv4 acc2[2][8] = {};
#pragma unroll
  for (int nt = 0; nt < 8; ++nt) {
    halfv8 bf = *(const halfv8*)&yw[(nt * 16 + lr) * YPITCH + lk * 8];
#pragma unroll
    for (int mt = 0; mt < 2; ++mt)
      acc2[mt][nt] = __builtin_amdgcn_mfma_f32_16x16x32_f16(am[mt], bf,
                                                            acc2[mt][nt], 0, 0, 0);
  }

  // (k) bias + relu + store H node-major: H[g][j*128 + o]
  half_t* Hg = H + (size_t)g * KDIM;
#pragma unroll
  for (int nt = 0; nt < 8; ++nt) {
    const float bias = gb[nt * 16 + lr];
#pragma unroll
    for (int mt = 0; mt < 2; ++mt)
#pragma unroll
      for (int q = 0; q < 4; ++q) {
        const int m = mt * 16 + lk * 4 + q;
        const float v = acc2[mt][nt][q] + bias;
        Hg[m * FIN + nt * 16 + lr] = (half_t)(v > 0.f ? v : 0.f);
      }
  }
}

// ---------------------------------------------------------------------------
// lin1 GEMM: C[m][n] = sum_k H[m][k] * w1p[n][k]; split-K=2 -> two fp16
// partial buffers. m97 structure: 128x128 tile, BK=32, 4 waves, gload_lds.
__global__ __launch_bounds__(256) void lin1_gemm(
    const half_t* __restrict__ A, const half_t* __restrict__ B,
    half_t* __restrict__ Cbase) {
  __shared__ __attribute__((aligned(16))) half_t As[128 * 32];  // 8 KB
  __shared__ __attribute__((aligned(16))) half_t Bs[128 * 32];  // 8 KB
  const int t = threadIdx.x;
  const int m0 = blockIdx.x * 128;
  const int n0 = blockIdx.y * 128;
  const int kz = blockIdx.z;
  const int k0 = kz * (KDIM / 2);
  half_t* C = Cbase + (size_t)kz * ((size_t)NBS * HID);

  const int w = t >> 6, l = t & 63;
  const int lr = l & 15, lk = l >> 4;
  const int wm = (w & 1) * 64, wn = (w >> 1) * 64;

  const int ch0 = t, ch1 = t + 256;           // 16B chunks of the 8KB tile
  const int r0 = ch0 >> 2, c0_ = (ch0 & 3) * 8;
  const int r1 = ch1 >> 2, c1_ = (ch1 & 3) * 8;
  const half_t* gA0 = A + (size_t)(m0 + r0) * KDIM + k0 + c0_;
  const half_t* gA1 = A + (size_t)(m0 + r1) * KDIM + k0 + c1_;
  const half_t* gB0 = B + (size_t)(n0 + r0) * KDIM + k0 + c0_;
  const half_t* gB1 = B + (size_t)(n0 + r1) * KDIM + k0 + c1_;

  floatv4 acc[4][4] = {};

  for (int kt = 0; kt < 64; ++kt) {
    GLDS16(gA0, &As[ch0 * 8]);
    GLDS16(gA1, &As[ch1 * 8]);
    GLDS16(gB0, &Bs[ch0 * 8]);
    GLDS16(gB1, &Bs[ch1 * 8]);
    gA0 += 32; gA1 += 32; gB0 += 32; gB1 += 32;
    __syncthreads();

    halfv8 af[4], bf[4];
#pragma unroll
    for (int mf = 0; mf < 4; ++mf)
      af[mf] = *(const halfv8*)&As[(wm + mf * 16 + lr) * 32 + lk * 8];
#pragma unroll
    for (int nf = 0; nf < 4; ++nf)
      bf[nf] = *(const halfv8*)&Bs[(wn + nf * 16 + lr) * 32 + lk * 8];
#pragma unroll
    for (int mf = 0; mf < 4; ++mf)
#pragma unroll
      for (int nf = 0; nf < 4; ++nf)
        acc[mf][nf] = __builtin_amdgcn_mfma_f32_16x16x32_f16(af[mf], bf[nf],
                                                             acc[mf][nf], 0, 0, 0);
    __syncthreads();
  }
#pragma unroll
  for (int mf = 0; mf < 4; ++mf)
#pragma unroll
    for (int nf = 0; nf < 4; ++nf) {
      const int n = n0 + wn + nf * 16 + lr;
#pragma unroll
      for (int j = 0; j < 4; ++j) {
        const int m = m0 + wm + mf * 16 + lk * 4 + j;
        C[(size_t)m * HID + n] = (half_t)acc[mf][nf][j];
      }
    }
}

// ---------------------------------------------------------------------------
// head: hidden = relu(C0+C1+b1); logits = hidden @ w2^T + b2; softmax -> out
__global__ __launch_bounds__(256) void head(
    const half_t* __restrict__ C0, const half_t* __restrict__ C1,
    const float* __restrict__ b1, const float* __restrict__ w2,
    const float* __restrict__ b2, float* __restrict__ out) {
  __shared__ __attribute__((aligned(16))) float w2s[NCLS * HID];  // 40 KB
  const int t = threadIdx.x;
  {
    const floatv4* s4 = (const floatv4*)w2;
    floatv4* d4 = (floatv4*)w2s;
    for (int i = t; i < (NCLS * HID) / 4; i += 256) d4[i] = s4[i];
  }
  __syncthreads();
  const int w = t >> 6, l = t & 63;
  const int row = blockIdx.x * 4 + w;
  const half_t* c0 = C0 + (size_t)row * HID;
  const half_t* c1 = C1 + (size_t)row * HID;

  float r[16];
#pragma unroll
  for (int jj = 0; jj < 4; ++jj) {
    halfv4 u = *(const halfv4*)&c0[jj * 256 + l * 4];
    halfv4 v = *(const halfv4*)&c1[jj * 256 + l * 4];
    floatv4 bb = *(const floatv4*)&b1[jj * 256 + l * 4];
#pragma unroll
    for (int q = 0; q < 4; ++q) {
      const float s = (float)u[q] + (float)v[q] + bb[q];
      r[jj * 4 + q] = s > 0.f ? s : 0.f;
    }
  }
  float lg[10];
#pragma unroll
  for (int c = 0; c < NCLS; ++c) {
    float p = 0.f;
#pragma unroll
    for (int jj = 0; jj < 4; ++jj) {
      floatv4 wv = *(const floatv4*)&w2s[c * HID + jj * 256 + l * 4];
      p += r[jj * 4 + 0] * wv[0] + r[jj * 4 + 1] * wv[1] +
           r[jj * 4 + 2] * wv[2] + r[jj * 4 + 3] * wv[3];
    }
#pragma unroll
    for (int off = 32; off >= 1; off >>= 1) p += __shfl_xor(p, off);
    lg[c] = p + b2[c];
  }
  float mx = lg[0];
#pragma unroll
  for (int c = 1; c < NCLS; ++c) mx = fmaxf(mx, lg[c]);
  float sum = 0.f;
#pragma unroll
  for (int c = 0; c < NCLS; ++c) { lg[c] = __expf(lg[c] - mx); sum += lg[c]; }
  const float inv = 1.f / sum;
  float myv = 0.f;
#pragma unroll
  for (int c = 0; c < NCLS; ++c) myv = (l == c) ? lg[c] * inv : myv;
  if (l < NCLS) out[(size_t)row * NCLS + l] = myv;
}

// ---------------------------------------------------------------------------
extern "C" void kernel_launch(void* const* d_in, const int* in_sizes, int n_in,
                              void* d_out, int out_size, void* d_ws, size_t ws_size,
                              hipStream_t stream) {
  (void)in_sizes; (void)n_in; (void)out_size; (void)ws_size;
  const float* x  = (const float*)d_in[0];
  const int*   ei = (const int*)d_in[1];
  const float* gw = (const float*)d_in[2];
  const float* gb = (const float*)d_in[3];
  const float* w1 = (const float*)d_in[4];
  const float* b1 = (const float*)d_in[5];
  const float* w2 = (const float*)d_in[6];
  const float* b2 = (const float*)d_in[7];
  float* out = (float*)d_out;

  char* ws = (char*)d_ws;
  half_t* H   = (half_t*)(ws);                        // 33,554,432 B
  half_t* w1p = (half_t*)(ws + 33554432);             //  8,388,608 B
  half_t* C01 = (half_t*)(ws + 33554432 + 8388608);   // 2x 8,388,608 B

  prep_w1  <<<dim3(HID),       dim3(256), 0, stream>>>(w1, w1p);
  gin_fused<<<dim3(NBS / 4),   dim3(256), 0, stream>>>(x, ei, gw, gb, H);
  lin1_gemm<<<dim3(32, 8, 2),  dim3(256), 0, stream>>>(H, w1p, C01);
  head     <<<dim3(NBS / 4),   dim3(256), 0, stream>>>(C01, C01 + (size_t)NBS * HID,
                                                       b1, w2, b2, out);
}

// Round 3
// 98.616 us; speedup vs baseline: 15.0379x; 1.0175x over previous
//
#include <hip/hip_runtime.h>

typedef _Float16 half_t;
typedef _Float16 halfv8 __attribute__((ext_vector_type(8)));
typedef _Float16 halfv4 __attribute__((ext_vector_type(4)));
typedef float    floatv4 __attribute__((ext_vector_type(4)));
typedef unsigned int uint;
typedef uint uintv4 __attribute__((ext_vector_type(4)));

#define NODES 32
#define FIN   128
#define EPG   512
#define NBS   4096
#define ETOT  (NBS*EPG)
#define HID   1024
#define KDIM  4096   // FIN*NODES
#define NCLS  10
#define WPITCH 136
#define YPITCH 36

// lin1 GEMM geometry
#define BM 256
#define BN 256
#define BK 64          // halves per LDS row (128 B = 32 banks)
#define KS 4           // split-K factor
#define KSLEN (KDIM/KS) // 1024
#define NT (KSLEN/BK)   // 16 K-tiles per block

// async global->LDS, 16B per lane (dest = wave-uniform base + lane*16)
#define GLDS16(g, l)                                                        \
  __builtin_amdgcn_global_load_lds(                                         \
      (const __attribute__((address_space(1))) unsigned int*)(g),           \
      (__attribute__((address_space(3))) unsigned int*)(l), 16, 0, 0)

// ---------------------------------------------------------------------------
// prep: lin1_w fp32 [o][f*32+n] -> fp16 permuted [o][n*128+f]
__global__ __launch_bounds__(256) void prep_w1(const float* __restrict__ w1,
                                               half_t* __restrict__ w1p) {
  __shared__ float tmp[FIN * 33];
  const int o = blockIdx.x, t = threadIdx.x;
  const floatv4* src = (const floatv4*)(w1 + (size_t)o * KDIM);
  for (int i = t; i < KDIM / 4; i += 256) {
    floatv4 v = src[i];
    const int f = i >> 3;
    const int n = (i & 7) * 4;
#pragma unroll
    for (int q = 0; q < 4; ++q) tmp[f * 33 + n + q] = v[q];
  }
  __syncthreads();
  half_t* dst = w1p + (size_t)o * KDIM;
  for (int i = t; i < KDIM; i += 256) {
    const int n = i >> 7, f = i & 127;
    dst[i] = (half_t)tmp[f * 33 + n];
  }
}

// ---------------------------------------------------------------------------
// Fused GIN conv via linearity: H_g = relu( (I + C_g) @ (x_g @ W^T) + b )
__global__ __launch_bounds__(256, 2) void gin_fused(
    const float* __restrict__ x, const int* __restrict__ ei,
    const float* __restrict__ gw, const float* __restrict__ gb,
    half_t* __restrict__ H) {
  __shared__ __attribute__((aligned(16))) half_t Ws[FIN * WPITCH];
  __shared__ __attribute__((aligned(16))) half_t Yt[4][FIN * YPITCH];
  __shared__ __attribute__((aligned(16))) uint  cnt[4][512];

  const int t = threadIdx.x, w = t >> 6, l = t & 63;
  const int lr = l & 15, lk = l >> 4;
  const int g = blockIdx.x * 4 + w;

  const float* xg = x + (size_t)g * (NODES * FIN);
  floatv4 xr[2][4][2];
#pragma unroll
  for (int mt = 0; mt < 2; ++mt)
#pragma unroll
    for (int kk = 0; kk < 4; ++kk) {
      const float* p = xg + (mt * 16 + lr) * FIN + kk * 32 + lk * 8;
      xr[mt][kk][0] = *(const floatv4*)p;
      xr[mt][kk][1] = *(const floatv4*)(p + 4);
    }
  const int* sp = ei + (size_t)g * EPG;
  const int* dp = ei + (size_t)ETOT + (size_t)g * EPG;
  uintv4 s0 = *(const uintv4*)(sp + l * 8);
  uintv4 s1 = *(const uintv4*)(sp + l * 8 + 4);
  uintv4 d0 = *(const uintv4*)(dp + l * 8);
  uintv4 d1 = *(const uintv4*)(dp + l * 8 + 4);

  {
    uintv4* c4 = (uintv4*)cnt[w];
    uintv4 z = {0, 0, 0, 0};
    c4[l] = z;
    c4[l + 64] = z;
  }
  for (int i = t; i < (FIN * FIN) / 4; i += 256) {
    const int o = i >> 5, kc = (i & 31) * 4;
    floatv4 v = *(const floatv4*)(gw + o * FIN + kc);
    halfv4 h = {(half_t)v[0], (half_t)v[1], (half_t)v[2], (half_t)v[3]};
    *(halfv4*)&Ws[o * WPITCH + kc] = h;
  }
  __syncthreads();

#pragma unroll
  for (int q = 0; q < 4; ++q) {
    uint p0 = (d0[q] & 31) * 32 + (s0[q] & 31);
    atomicAdd(&cnt[w][p0 >> 1], 1u << ((p0 & 1) * 16));
    uint p1 = (d1[q] & 31) * 32 + (s1[q] & 31);
    atomicAdd(&cnt[w][p1 >> 1], 1u << ((p1 & 1) * 16));
  }

  halfv8 af[2][4];
#pragma unroll
  for (int mt = 0; mt < 2; ++mt)
#pragma unroll
    for (int kk = 0; kk < 4; ++kk) {
      halfv8 h;
#pragma unroll
      for (int q = 0; q < 4; ++q) {
        h[q]     = (half_t)xr[mt][kk][0][q];
        h[q + 4] = (half_t)xr[mt][kk][1][q];
      }
      af[mt][kk] = h;
    }

  floatv4 acc[2][8] = {};
#pragma unroll
  for (int kk = 0; kk < 4; ++kk)
#pragma unroll
    for (int nt = 0; nt < 8; ++nt) {
      halfv8 bf = *(const halfv8*)&Ws[(nt * 16 + lr) * WPITCH + kk * 32 + lk * 8];
#pragma unroll
      for (int mt = 0; mt < 2; ++mt)
        acc[mt][nt] = __builtin_amdgcn_mfma_f32_16x16x32_f16(af[mt][kk], bf,
                                                             acc[mt][nt], 0, 0, 0);
    }

  half_t* yw = Yt[w];
#pragma unroll
  for (int mt = 0; mt < 2; ++mt)
#pragma unroll
    for (int nt = 0; nt < 8; ++nt) {
      halfv4 h = {(half_t)acc[mt][nt][0], (half_t)acc[mt][nt][1],
                  (half_t)acc[mt][nt][2], (half_t)acc[mt][nt][3]};
      *(halfv4*)&yw[(nt * 16 + lr) * YPITCH + mt * 16 + lk * 4] = h;
    }

  const unsigned short* c16 = (const unsigned short*)cnt[w];
  halfv8 am[2];
#pragma unroll
  for (int mt = 0; mt < 2; ++mt) {
    const int i = mt * 16 + lr;
#pragma unroll
    for (int q = 0; q < 8; ++q) {
      const int j = lk * 8 + q;
      float c = (float)c16[i * 32 + j] + ((j == i) ? 1.f : 0.f);
      am[mt][q] = (half_t)c;
    }
  }

  floatv4 acc2[2][8] = {};
#pragma unroll
  for (int nt = 0; nt < 8; ++nt) {
    halfv8 bf = *(const halfv8*)&yw[(nt * 16 + lr) * YPITCH + lk * 8];
#pragma unroll
    for (int mt = 0; mt < 2; ++mt)
      acc2[mt][nt] = __builtin_amdgcn_mfma_f32_16x16x32_f16(am[mt], bf,
                                                            acc2[mt][nt], 0, 0, 0);
  }

  half_t* Hg = H + (size_t)g * KDIM;
#pragma unroll
  for (int nt = 0; nt < 8; ++nt) {
    const float bias = gb[nt * 16 + lr];
#pragma unroll
    for (int mt = 0; mt < 2; ++mt)
#pragma unroll
      for (int q = 0; q < 4; ++q) {
        const int m = mt * 16 + lk * 4 + q;
        const float v = acc2[mt][nt][q] + bias;
        Hg[m * FIN + nt * 16 + lr] = (half_t)(v > 0.f ? v : 0.f);
      }
  }
}

// ---------------------------------------------------------------------------
// lin1 GEMM, 256x256 tile, BK=64, 8 waves, split-K=4.
// T2: chunk-XOR LDS swizzle (source-side for gload_lds, matching read-side).
// T3+T4: double-buffer + 2-tile-lookahead staging, counted vmcnt(8).
// T5: setprio around MFMA clusters.  C[ks][m][n] fp16 partials.
__global__ __launch_bounds__(512, 2) void lin1_gemm(
    const half_t* __restrict__ A, const half_t* __restrict__ B,
    half_t* __restrict__ Cbase) {
  __shared__ __attribute__((aligned(16))) half_t As[2][BM * BK];  // 64 KB
  __shared__ __attribute__((aligned(16))) half_t Bs[2][BN * BK];  // 64 KB

  const int t = threadIdx.x;
  // bijective XCD swizzle (256 blocks, 256%8==0): m fastest within an XCD
  const int orig = blockIdx.x;
  const int wg = (orig & 7) * 32 + (orig >> 3);
  const int mt = wg & 15, rest = wg >> 4;
  const int nt_ = rest & 3, ks = rest >> 2;
  const int m0 = mt * BM, n0 = nt_ * BN, k0 = ks * KSLEN;

  // staging geometry: thread covers 16B chunks L = t + j*512 (row=L>>3, col=L&7)
  // LDS[r][c] <- G[r][c ^ (r&7)]  (swizzle on the global source side)
  const half_t* gA[4];
  const half_t* gB[4];
#pragma unroll
  for (int j = 0; j < 4; ++j) {
    const int L = t + j * 512;
    const int r = L >> 3;
    const int c = (L & 7) ^ (r & 7);
    gA[j] = A + (size_t)(m0 + r) * KDIM + k0 + c * 8;
    gB[j] = B + (size_t)(n0 + r) * KDIM + k0 + c * 8;
  }

#define STAGE(buf, koff)                                                    \
  {                                                                         \
    _Pragma("unroll")                                                       \
    for (int j = 0; j < 4; ++j)                                             \
      GLDS16(gA[j] + (koff), &As[buf][(t + j * 512) * 8]);                  \
    _Pragma("unroll")                                                       \
    for (int j = 0; j < 4; ++j)                                             \
      GLDS16(gB[j] + (koff), &Bs[buf][(t + j * 512) * 8]);                  \
  }

  const int w = t >> 6, l = t & 63, lr = l & 15, lk = l >> 4;
  const int wm = (w >> 2) * 128, wn = (w & 3) * 64;

  floatv4 acc[8][4] = {};

  // prologue: stage tiles 0,1; gate tile 0
  STAGE(0, 0)
  STAGE(1, BK)
  asm volatile("s_waitcnt vmcnt(8)" ::: "memory");
  __builtin_amdgcn_s_barrier();

  for (int kt = 0; kt < NT; ++kt) {
    const int cur = kt & 1;
    const half_t* as = As[cur];
    const half_t* bs = Bs[cur];
    halfv8 bf[4], af[4];
#pragma unroll
    for (int ksb = 0; ksb < 2; ++ksb) {
      // ---- phase A: read B(ksb) + A rows 0-63 (mf 0..3), 16 MFMA
#pragma unroll
      for (int nf = 0; nf < 4; ++nf) {
        const int row = wn + nf * 16 + lr;
        const int ch = (ksb * 4 + lk) ^ (row & 7);
        bf[nf] = *(const halfv8*)&bs[row * BK + ch * 8];
      }
#pragma unroll
      for (int mf = 0; mf < 4; ++mf) {
        const int row = wm + mf * 16 + lr;
        const int ch = (ksb * 4 + lk) ^ (row & 7);
        af[mf] = *(const halfv8*)&as[row * BK + ch * 8];
      }
      __builtin_amdgcn_s_barrier();
      asm volatile("s_waitcnt lgkmcnt(0)" ::: "memory");
      __builtin_amdgcn_sched_barrier(0);
      __builtin_amdgcn_s_setprio(1);
#pragma unroll
      for (int mf = 0; mf < 4; ++mf)
#pragma unroll
        for (int nf = 0; nf < 4; ++nf)
          acc[mf][nf] = __builtin_amdgcn_mfma_f32_16x16x32_f16(
              af[mf], bf[nf], acc[mf][nf], 0, 0, 0);
      __builtin_amdgcn_s_setprio(0);
      __builtin_amdgcn_s_barrier();
      // ---- phase B: read A rows 64-127 (mf 4..7), 16 MFMA (reuse bf)
#pragma unroll
      for (int mf = 0; mf < 4; ++mf) {
        const int row = wm + 64 + mf * 16 + lr;
        const int ch = (ksb * 4 + lk) ^ (row & 7);
        af[mf] = *(const halfv8*)&as[row * BK + ch * 8];
      }
      __builtin_amdgcn_s_barrier();
      asm volatile("s_waitcnt lgkmcnt(0)" ::: "memory");
      __builtin_amdgcn_sched_barrier(0);
      __builtin_amdgcn_s_setprio(1);
#pragma unroll
      for (int mf = 0; mf < 4; ++mf)
#pragma unroll
        for (int nf = 0; nf < 4; ++nf)
          acc[mf + 4][nf] = __builtin_amdgcn_mfma_f32_16x16x32_f16(
              af[mf], bf[nf], acc[mf + 4][nf], 0, 0, 0);
      __builtin_amdgcn_s_setprio(0);
      __builtin_amdgcn_s_barrier();
    }
    // stage tile kt+2 into buf[cur] (fully consumed above); gate tile kt+1
    const int src = (kt + 2 < NT) ? (kt + 2) : 0;  // dummy re-stage keeps vmcnt uniform
    STAGE(cur, src * BK)
    asm volatile("s_waitcnt vmcnt(8)" ::: "memory");
    __builtin_amdgcn_s_barrier();
  }

  // epilogue: fp16 partial store
  half_t* C = Cbase + (size_t)ks * ((size_t)NBS * HID);
#pragma unroll
  for (int mf = 0; mf < 8; ++mf)
#pragma unroll
    for (int nf = 0; nf < 4; ++nf) {
      const int n = n0 + wn + nf * 16 + lr;
#pragma unroll
      for (int q = 0; q < 4; ++q) {
        const int m = m0 + wm + mf * 16 + lk * 4 + q;
        C[(size_t)m * HID + n] = (half_t)acc[mf][nf][q];
      }
    }
#undef STAGE
}

// ---------------------------------------------------------------------------
// head: hidden = relu(sum_ks C[ks] + b1); logits = hidden @ w2^T + b2; softmax
__global__ __launch_bounds__(256) void head(
    const half_t* __restrict__ Cb, const float* __restrict__ b1,
    const float* __restrict__ w2, const float* __restrict__ b2,
    float* __restrict__ out) {
  __shared__ __attribute__((aligned(16))) float w2s[NCLS * HID];
  const int t = threadIdx.x;
  {
    const floatv4* s4 = (const floatv4*)w2;
    floatv4* d4 = (floatv4*)w2s;
    for (int i = t; i < (NCLS * HID) / 4; i += 256) d4[i] = s4[i];
  }
  __syncthreads();
  const int w = t >> 6, l = t & 63;
  const int row = blockIdx.x * 4 + w;

  float r[16];
#pragma unroll
  for (int jj = 0; jj < 4; ++jj) {
    floatv4 bb = *(const floatv4*)&b1[jj * 256 + l * 4];
    float s[4] = {bb[0], bb[1], bb[2], bb[3]};
#pragma unroll
    for (int p = 0; p < KS; ++p) {
      const half_t* cp = Cb + (size_t)p * ((size_t)NBS * HID) + (size_t)row * HID;
      halfv4 u = *(const halfv4*)&cp[jj * 256 + l * 4];
#pragma unroll
      for (int q = 0; q < 4; ++q) s[q] += (float)u[q];
    }
#pragma unroll
    for (int q = 0; q < 4; ++q) r[jj * 4 + q] = s[q] > 0.f ? s[q] : 0.f;
  }
  float lg[10];
#pragma unroll
  for (int c = 0; c < NCLS; ++c) {
    float p = 0.f;
#pragma unroll
    for (int jj = 0; jj < 4; ++jj) {
      floatv4 wv = *(const floatv4*)&w2s[c * HID + jj * 256 + l * 4];
      p += r[jj * 4 + 0] * wv[0] + r[jj * 4 + 1] * wv[1] +
           r[jj * 4 + 2] * wv[2] + r[jj * 4 + 3] * wv[3];
    }
#pragma unroll
    for (int off = 32; off >= 1; off >>= 1) p += __shfl_xor(p, off);
    lg[c] = p + b2[c];
  }
  float mx = lg[0];
#pragma unroll
  for (int c = 1; c < NCLS; ++c) mx = fmaxf(mx, lg[c]);
  float sum = 0.f;
#pragma unroll
  for (int c = 0; c < NCLS; ++c) { lg[c] = __expf(lg[c] - mx); sum += lg[c]; }
  const float inv = 1.f / sum;
  float myv = 0.f;
#pragma unroll
  for (int c = 0; c < NCLS; ++c) myv = (l == c) ? lg[c] * inv : myv;
  if (l < NCLS) out[(size_t)row * NCLS + l] = myv;
}

// ---------------------------------------------------------------------------
extern "C" void kernel_launch(void* const* d_in, const int* in_sizes, int n_in,
                              void* d_out, int out_size, void* d_ws, size_t ws_size,
                              hipStream_t stream) {
  (void)in_sizes; (void)n_in; (void)out_size; (void)ws_size;
  const float* x  = (const float*)d_in[0];
  const int*   ei = (const int*)d_in[1];
  const float* gw = (const float*)d_in[2];
  const float* gb = (const float*)d_in[3];
  const float* w1 = (const float*)d_in[4];
  const float* b1 = (const float*)d_in[5];
  const float* w2 = (const float*)d_in[6];
  const float* b2 = (const float*)d_in[7];
  float* out = (float*)d_out;

  char* ws = (char*)d_ws;
  half_t* H   = (half_t*)(ws);                        // 32 MB
  half_t* w1p = (half_t*)(ws + 33554432);             //  8 MB
  half_t* C   = (half_t*)(ws + 33554432 + 8388608);   // KS x 8 MB = 32 MB

  prep_w1  <<<dim3(HID),     dim3(256), 0, stream>>>(w1, w1p);
  gin_fused<<<dim3(NBS / 4), dim3(256), 0, stream>>>(x, ei, gw, gb, H);
  lin1_gemm<<<dim3(16 * 4 * KS), dim3(512), 0, stream>>>(H, w1p, C);
  head     <<<dim3(NBS / 4), dim3(256), 0, stream>>>(C, b1, w2, b2, out);
}

// Round 4
// 92.536 us; speedup vs baseline: 16.0259x; 1.0657x over previous
//
#include <hip/hip_runtime.h>

typedef _Float16 half_t;
typedef _Float16 halfv8 __attribute__((ext_vector_type(8)));
typedef _Float16 halfv4 __attribute__((ext_vector_type(4)));
typedef float    floatv4 __attribute__((ext_vector_type(4)));
typedef unsigned int uint;
typedef uint uintv4 __attribute__((ext_vector_type(4)));

#define NODES 32
#define FIN   128
#define EPG   512
#define NBS   4096
#define ETOT  (NBS*EPG)
#define HID   1024
#define KDIM  4096   // FIN*NODES
#define NCLS  10
#define WPITCH 136
#define YPITCH 36

// lin1 GEMM geometry
#define BM 256
#define BN 256
#define BK 64          // halves per LDS row (128 B)
#define KS 4           // split-K factor
#define KSLEN (KDIM/KS) // 1024
#define NT (KSLEN/BK)   // 16 K-tiles per block

// async global->LDS, 16B per lane (dest = wave-uniform base + lane*16)
#define GLDS16(g, l)                                                        \
  __builtin_amdgcn_global_load_lds(                                         \
      (const __attribute__((address_space(1))) unsigned int*)(g),           \
      (__attribute__((address_space(3))) unsigned int*)(l), 16, 0, 0)

// ---------------------------------------------------------------------------
// prep: lin1_w fp32 [o][f*32+n] -> fp16 permuted [o][n*128+f]
__global__ __launch_bounds__(256) void prep_w1(const float* __restrict__ w1,
                                               half_t* __restrict__ w1p) {
  __shared__ float tmp[FIN * 33];
  const int o = blockIdx.x, t = threadIdx.x;
  const floatv4* src = (const floatv4*)(w1 + (size_t)o * KDIM);
  for (int i = t; i < KDIM / 4; i += 256) {
    floatv4 v = src[i];
    const int f = i >> 3;
    const int n = (i & 7) * 4;
#pragma unroll
    for (int q = 0; q < 4; ++q) tmp[f * 33 + n + q] = v[q];
  }
  __syncthreads();
  half_t* dst = w1p + (size_t)o * KDIM;
  for (int i = t; i < KDIM; i += 256) {
    const int n = i >> 7, f = i & 127;
    dst[i] = (half_t)tmp[f * 33 + n];
  }
}

// ---------------------------------------------------------------------------
// Fused GIN conv via linearity: H_g = relu( (I + C_g) @ (x_g @ W^T) + b )
__global__ __launch_bounds__(256, 2) void gin_fused(
    const float* __restrict__ x, const int* __restrict__ ei,
    const float* __restrict__ gw, const float* __restrict__ gb,
    half_t* __restrict__ H) {
  __shared__ __attribute__((aligned(16))) half_t Ws[FIN * WPITCH];
  __shared__ __attribute__((aligned(16))) half_t Yt[4][FIN * YPITCH];
  __shared__ __attribute__((aligned(16))) uint  cnt[4][512];

  const int t = threadIdx.x, w = t >> 6, l = t & 63;
  const int lr = l & 15, lk = l >> 4;
  const int g = blockIdx.x * 4 + w;

  const float* xg = x + (size_t)g * (NODES * FIN);
  floatv4 xr[2][4][2];
#pragma unroll
  for (int mt = 0; mt < 2; ++mt)
#pragma unroll
    for (int kk = 0; kk < 4; ++kk) {
      const float* p = xg + (mt * 16 + lr) * FIN + kk * 32 + lk * 8;
      xr[mt][kk][0] = *(const floatv4*)p;
      xr[mt][kk][1] = *(const floatv4*)(p + 4);
    }
  const int* sp = ei + (size_t)g * EPG;
  const int* dp = ei + (size_t)ETOT + (size_t)g * EPG;
  uintv4 s0 = *(const uintv4*)(sp + l * 8);
  uintv4 s1 = *(const uintv4*)(sp + l * 8 + 4);
  uintv4 d0 = *(const uintv4*)(dp + l * 8);
  uintv4 d1 = *(const uintv4*)(dp + l * 8 + 4);

  {
    uintv4* c4 = (uintv4*)cnt[w];
    uintv4 z = {0, 0, 0, 0};
    c4[l] = z;
    c4[l + 64] = z;
  }
  for (int i = t; i < (FIN * FIN) / 4; i += 256) {
    const int o = i >> 5, kc = (i & 31) * 4;
    floatv4 v = *(const floatv4*)(gw + o * FIN + kc);
    halfv4 h = {(half_t)v[0], (half_t)v[1], (half_t)v[2], (half_t)v[3]};
    *(halfv4*)&Ws[o * WPITCH + kc] = h;
  }
  __syncthreads();

#pragma unroll
  for (int q = 0; q < 4; ++q) {
    uint p0 = (d0[q] & 31) * 32 + (s0[q] & 31);
    atomicAdd(&cnt[w][p0 >> 1], 1u << ((p0 & 1) * 16));
    uint p1 = (d1[q] & 31) * 32 + (s1[q] & 31);
    atomicAdd(&cnt[w][p1 >> 1], 1u << ((p1 & 1) * 16));
  }

  halfv8 af[2][4];
#pragma unroll
  for (int mt = 0; mt < 2; ++mt)
#pragma unroll
    for (int kk = 0; kk < 4; ++kk) {
      halfv8 h;
#pragma unroll
      for (int q = 0; q < 4; ++q) {
        h[q]     = (half_t)xr[mt][kk][0][q];
        h[q + 4] = (half_t)xr[mt][kk][1][q];
      }
      af[mt][kk] = h;
    }

  floatv4 acc[2][8] = {};
#pragma unroll
  for (int kk = 0; kk < 4; ++kk)
#pragma unroll
    for (int nt = 0; nt < 8; ++nt) {
      halfv8 bf = *(const halfv8*)&Ws[(nt * 16 + lr) * WPITCH + kk * 32 + lk * 8];
#pragma unroll
      for (int mt = 0; mt < 2; ++mt)
        acc[mt][nt] = __builtin_amdgcn_mfma_f32_16x16x32_f16(af[mt][kk], bf,
                                                             acc[mt][nt], 0, 0, 0);
    }

  half_t* yw = Yt[w];
#pragma unroll
  for (int mt = 0; mt < 2; ++mt)
#pragma unroll
    for (int nt = 0; nt < 8; ++nt) {
      halfv4 h = {(half_t)acc[mt][nt][0], (half_t)acc[mt][nt][1],
                  (half_t)acc[mt][nt][2], (half_t)acc[mt][nt][3]};
      *(halfv4*)&yw[(nt * 16 + lr) * YPITCH + mt * 16 + lk * 4] = h;
    }

  const unsigned short* c16 = (const unsigned short*)cnt[w];
  halfv8 am[2];
#pragma unroll
  for (int mt = 0; mt < 2; ++mt) {
    const int i = mt * 16 + lr;
#pragma unroll
    for (int q = 0; q < 8; ++q) {
      const int j = lk * 8 + q;
      float c = (float)c16[i * 32 + j] + ((j == i) ? 1.f : 0.f);
      am[mt][q] = (half_t)c;
    }
  }

  floatv4 acc2[2][8] = {};
#pragma unroll
  for (int nt = 0; nt < 8; ++nt) {
    halfv8 bf = *(const halfv8*)&yw[(nt * 16 + lr) * YPITCH + lk * 8];
#pragma unroll
    for (int mt = 0; mt < 2; ++mt)
      acc2[mt][nt] = __builtin_amdgcn_mfma_f32_16x16x32_f16(am[mt], bf,
                                                            acc2[mt][nt], 0, 0, 0);
  }

  half_t* Hg = H + (size_t)g * KDIM;
#pragma unroll
  for (int nt = 0; nt < 8; ++nt) {
    const float bias = gb[nt * 16 + lr];
#pragma unroll
    for (int mt = 0; mt < 2; ++mt)
#pragma unroll
      for (int q = 0; q < 4; ++q) {
        const int m = mt * 16 + lk * 4 + q;
        const float v = acc2[mt][nt][q] + bias;
        Hg[m * FIN + nt * 16 + lr] = (half_t)(v > 0.f ? v : 0.f);
      }
  }
}

// ---------------------------------------------------------------------------
// lin1 GEMM, 256x256 tile, BK=64, 8 waves, split-K=4.
// De-lockstepped: per K-tile, each wave runs its full 64-MFMA chain with
// compiler-scheduled lgkmcnt; only 2 barriers per K-tile (close-reads +
// post-stage gate). Counted vmcnt(8), 1-tile lookahead staging.
__global__ __launch_bounds__(512, 2) void lin1_gemm(
    const half_t* __restrict__ A, const half_t* __restrict__ B,
    half_t* __restrict__ Cbase) {
  __shared__ __attribute__((aligned(16))) half_t As[2][BM * BK];  // 64 KB
  __shared__ __attribute__((aligned(16))) half_t Bs[2][BN * BK];  // 64 KB

  const int t = threadIdx.x;
  // bijective XCD swizzle (256 blocks): m fastest within an XCD
  const int orig = blockIdx.x;
  const int wg = (orig & 7) * 32 + (orig >> 3);
  const int mt = wg & 15, rest = wg >> 4;
  const int nt_ = rest & 3, ks = rest >> 2;
  const int m0 = mt * BM, n0 = nt_ * BN, k0 = ks * KSLEN;

  // staging: thread covers 16B chunks L = t + j*512 (row=L>>3, chunk=L&7);
  // source pre-swizzled: LDS[r][c] <- G[r][c ^ (r&7)]
  const half_t* gA[4];
  const half_t* gB[4];
#pragma unroll
  for (int j = 0; j < 4; ++j) {
    const int L = t + j * 512;
    const int r = L >> 3;
    const int c = (L & 7) ^ (r & 7);
    gA[j] = A + (size_t)(m0 + r) * KDIM + k0 + c * 8;
    gB[j] = B + (size_t)(n0 + r) * KDIM + k0 + c * 8;
  }

#define STAGE(buf, koff)                                                    \
  {                                                                         \
    _Pragma("unroll")                                                       \
    for (int j = 0; j < 4; ++j)                                             \
      GLDS16(gA[j] + (koff), &As[buf][(t + j * 512) * 8]);                  \
    _Pragma("unroll")                                                       \
    for (int j = 0; j < 4; ++j)                                             \
      GLDS16(gB[j] + (koff), &Bs[buf][(t + j * 512) * 8]);                  \
  }

  const int w = t >> 6, l = t & 63, lr = l & 15, lk = l >> 4;
  const int wm = (w >> 2) * 128, wn = (w & 3) * 64;

  floatv4 acc[8][4] = {};

  // prologue: stage tiles 0,1; gate tile 0
  STAGE(0, 0)
  STAGE(1, BK)
  asm volatile("s_waitcnt vmcnt(8)" ::: "memory");
  __builtin_amdgcn_s_barrier();

  for (int kt = 0; kt < NT; ++kt) {
    const int cur = kt & 1;
    const half_t* as = As[cur];
    const half_t* bs = Bs[cur];
#pragma unroll
    for (int ksb = 0; ksb < 2; ++ksb) {
      halfv8 bf[4], af[8];
#pragma unroll
      for (int nf = 0; nf < 4; ++nf) {
        const int row = wn + nf * 16 + lr;
        const int ch = (ksb * 4 + lk) ^ (row & 7);
        bf[nf] = *(const halfv8*)&bs[row * BK + ch * 8];
      }
#pragma unroll
      for (int mf = 0; mf < 8; ++mf) {
        const int row = wm + mf * 16 + lr;
        const int ch = (ksb * 4 + lk) ^ (row & 7);
        af[mf] = *(const halfv8*)&as[row * BK + ch * 8];
      }
      __builtin_amdgcn_s_setprio(1);
#pragma unroll
      for (int mf = 0; mf < 8; ++mf)
#pragma unroll
        for (int nf = 0; nf < 4; ++nf)
          acc[mf][nf] = __builtin_amdgcn_mfma_f32_16x16x32_f16(
              af[mf], bf[nf], acc[mf][nf], 0, 0, 0);
      __builtin_amdgcn_s_setprio(0);
    }
    // all waves done reading buf[cur] -> safe to restage it
    __builtin_amdgcn_s_barrier();
    const int src = (kt + 2 < NT) ? (kt + 2) : 0;  // dummy keeps vmcnt uniform
    STAGE(cur, src * BK)
    asm volatile("s_waitcnt vmcnt(8)" ::: "memory");  // tile kt+1 landed
    __builtin_amdgcn_s_barrier();
  }

  // epilogue: fp16 partial store
  half_t* C = Cbase + (size_t)ks * ((size_t)NBS * HID);
#pragma unroll
  for (int mf = 0; mf < 8; ++mf)
#pragma unroll
    for (int nf = 0; nf < 4; ++nf) {
      const int n = n0 + wn + nf * 16 + lr;
#pragma unroll
      for (int q = 0; q < 4; ++q) {
        const int m = m0 + wm + mf * 16 + lk * 4 + q;
        C[(size_t)m * HID + n] = (half_t)acc[mf][nf][q];
      }
    }
#undef STAGE
}

// ---------------------------------------------------------------------------
// head: hidden = relu(sum_ks C[ks] + b1); logits = hidden @ w2^T + b2; softmax
__global__ __launch_bounds__(256) void head(
    const half_t* __restrict__ Cb, const float* __restrict__ b1,
    const float* __restrict__ w2, const float* __restrict__ b2,
    float* __restrict__ out) {
  __shared__ __attribute__((aligned(16))) float w2s[NCLS * HID];
  const int t = threadIdx.x;
  {
    const floatv4* s4 = (const floatv4*)w2;
    floatv4* d4 = (floatv4*)w2s;
    for (int i = t; i < (NCLS * HID) / 4; i += 256) d4[i] = s4[i];
  }
  __syncthreads();
  const int w = t >> 6, l = t & 63;
  const int row = blockIdx.x * 4 + w;

  float r[16];
#pragma unroll
  for (int jj = 0; jj < 4; ++jj) {
    floatv4 bb = *(const floatv4*)&b1[jj * 256 + l * 4];
    float s[4] = {bb[0], bb[1], bb[2], bb[3]};
#pragma unroll
    for (int p = 0; p < KS; ++p) {
      const half_t* cp = Cb + (size_t)p * ((size_t)NBS * HID) + (size_t)row * HID;
      halfv4 u = *(const halfv4*)&cp[jj * 256 + l * 4];
#pragma unroll
      for (int q = 0; q < 4; ++q) s[q] += (float)u[q];
    }
#pragma unroll
    for (int q = 0; q < 4; ++q) r[jj * 4 + q] = s[q] > 0.f ? s[q] : 0.f;
  }
  float lg[10];
#pragma unroll
  for (int c = 0; c < NCLS; ++c) {
    float p = 0.f;
#pragma unroll
    for (int jj = 0; jj < 4; ++jj) {
      floatv4 wv = *(const floatv4*)&w2s[c * HID + jj * 256 + l * 4];
      p += r[jj * 4 + 0] * wv[0] + r[jj * 4 + 1] * wv[1] +
           r[jj * 4 + 2] * wv[2] + r[jj * 4 + 3] * wv[3];
    }
#pragma unroll
    for (int off = 32; off >= 1; off >>= 1) p += __shfl_xor(p, off);
    lg[c] = p + b2[c];
  }
  float mx = lg[0];
#pragma unroll
  for (int c = 1; c < NCLS; ++c) mx = fmaxf(mx, lg[c]);
  float sum = 0.f;
#pragma unroll
  for (int c = 0; c < NCLS; ++c) { lg[c] = __expf(lg[c] - mx); sum += lg[c]; }
  const float inv = 1.f / sum;
  float myv = 0.f;
#pragma unroll
  for (int c = 0; c < NCLS; ++c) myv = (l == c) ? lg[c] * inv : myv;
  if (l < NCLS) out[(size_t)row * NCLS + l] = myv;
}

// ---------------------------------------------------------------------------
extern "C" void kernel_launch(void* const* d_in, const int* in_sizes, int n_in,
                              void* d_out, int out_size, void* d_ws, size_t ws_size,
                              hipStream_t stream) {
  (void)in_sizes; (void)n_in; (void)out_size; (void)ws_size;
  const float* x  = (const float*)d_in[0];
  const int*   ei = (const int*)d_in[1];
  const float* gw = (const float*)d_in[2];
  const float* gb = (const float*)d_in[3];
  const float* w1 = (const float*)d_in[4];
  const float* b1 = (const float*)d_in[5];
  const float* w2 = (const float*)d_in[6];
  const float* b2 = (const float*)d_in[7];
  float* out = (float*)d_out;

  char* ws = (char*)d_ws;
  half_t* H   = (half_t*)(ws);                        // 32 MB
  half_t* w1p = (half_t*)(ws + 33554432);             //  8 MB
  half_t* C   = (half_t*)(ws + 33554432 + 8388608);   // KS x 8 MB = 32 MB

  prep_w1  <<<dim3(HID),     dim3(256), 0, stream>>>(w1, w1p);
  gin_fused<<<dim3(NBS / 4), dim3(256), 0, stream>>>(x, ei, gw, gb, H);
  lin1_gemm<<<dim3(16 * 4 * KS), dim3(512), 0, stream>>>(H, w1p, C);
  head     <<<dim3(NBS / 4), dim3(256), 0, stream>>>(C, b1, w2, b2, out);
}